// Round 7
// baseline (3906.277 us; speedup 1.0000x reference)
//
#include <hip/hip_runtime.h>

#define B_ 128
#define T_ 256
#define L_ 4
#define DC_ 128
#define DW_ 128
#define H_ 256
#define V_ 6000
#define Z4_ 1024   // 4*H
#define S_ 8       // blocks per group (z-column split)
#define R_ 4       // batch rows per group
#define G_ 32      // groups = B/R
#define HC_ 32     // h-chunk per block = H/S
#define NEGF -1e30f

// d_ws layout (bytes)
#define WS_FLAGS 0                            // 256 u32 (+pad to 4096)
#define WS_VTAB  4096                         // V*L*DW f32 = 12,288,000
#define WS_NH    (WS_VTAB + V_*L_*DW_*4)      // [2][G][R*H] f32 = 1 MB

__device__ __forceinline__ float sigm(float x) { return 1.0f / (1.0f + expf(-x)); }
__device__ __forceinline__ void st_a(float* p, float v) {
  __hip_atomic_store(p, v, __ATOMIC_RELAXED, __HIP_MEMORY_SCOPE_AGENT);
}
__device__ __forceinline__ float ld_a(const float* p) {
  return __hip_atomic_load(p, __ATOMIC_RELAXED, __HIP_MEMORY_SCOPE_AGENT);
}
// wave-broadcast from lane l via v_readlane (VALU pipe, no LDS unit)
__device__ __forceinline__ float bcast(float v, int l) {
  return __int_as_float(__builtin_amdgcn_readlane(__float_as_int(v), l));
}
__device__ __forceinline__ int amax4(const float* sc) {   // first-max-wins (jnp.argmax)
  float bs = sc[0]; int bw = 0;
  if (sc[1] > bs) { bs = sc[1]; bw = 1; }
  if (sc[2] > bs) { bs = sc[2]; bw = 2; }
  if (sc[3] > bs) { bs = sc[3]; bw = 3; }
  return bw;
}
__device__ __forceinline__ float invlen(int w) {
  return (w == 0) ? 1.0f : (w == 1) ? 0.5f : (w == 2) ? (1.0f / 3.0f) : 0.25f;
}

// ------------------------------------------------------------------
// Kernel 1: vocab composition table (unchanged — verified).
// ------------------------------------------------------------------
__global__ __launch_bounds__(512) void vtab_kernel(
    const float* __restrict__ char_emb, const float* __restrict__ reset_W,
    const float* __restrict__ reset_b, const float* __restrict__ com_W,
    const float* __restrict__ com_b, float* __restrict__ Vtab)
{
  const int v = blockIdx.x;
  const int tid = threadIdx.x;
  const int w = tid >> 7;
  const int e = tid & 127;
  __shared__ float emb[DC_];
  __shared__ float ge[L_][DC_];
  if (tid < DC_) emb[tid] = char_emb[v * DC_ + tid];
  __syncthreads();
  float acc = reset_b[w * DC_ + e];
  const float* W = reset_W + (size_t)w * DC_ * DC_;
  #pragma unroll 8
  for (int k = 0; k < DC_; ++k) acc = fmaf(emb[k], W[k * DC_ + e], acc);
  ge[w][e] = sigm(acc) * emb[e];
  __syncthreads();
  float acc2 = com_b[e];
  #pragma unroll 8
  for (int k = 0; k < DC_; ++k) acc2 = fmaf(ge[w][k], com_W[k * DW_ + e], acc2);
  Vtab[((size_t)v * L_ + w) * DW_ + e] = tanhf(acc2);
}

// ------------------------------------------------------------------
// Kernel 2: distributed scan, S=8 x R=4, blk = s*32+g, 512 threads.
// Round-7 protocol: single nh mailbox (128 B/block/step), flag
// published right after the gates; receivers recompute pred(t-1)
// themselves (fused into the zh matvec k-loop). 5 barriers/step.
// ------------------------------------------------------------------
__global__ __launch_bounds__(512) void seq_kernel(
    const int* __restrict__ chars, const float* __restrict__ Vtab,
    const float* __restrict__ Kmat, const float* __restrict__ lstm_bias,
    const float* __restrict__ pred_W, const float* __restrict__ pred_b,
    const float* __restrict__ score_U, const float* __restrict__ bos,
    float* __restrict__ out, unsigned int* __restrict__ flags,
    float* __restrict__ nh_mb)
{
  const int blk = blockIdx.x;
  const int s = blk >> 5;     // 0..7 column-split index
  const int g = blk & 31;     // group (4 batch rows)
  const int tid = threadIdx.x;
  const int lane = tid & 63;
  const int row0 = g * R_;

  __shared__ float ringVt[R_][4][512];               // 32 KB
  __shared__ float pring[4][R_][DW_];                // 8 KB
  __shared__ float zring[4][R_][128];                // 8 KB (+bos z scratch)
  __shared__ float cring[4][R_][HC_];                // 2 KB
  __shared__ float part[4][R_][128];                 // 8 KB (zh partials)
  __shared__ float ppart[4][R_][128];                // 8 KB (pred / zx partials)
  __shared__ float h1tmp[H_];                        // 1 KB (init only)
  __shared__ int   charsL[R_][T_];                   // 4 KB
  __shared__ float biasC[128], UL[128], pbL[128];
  __shared__ float scL[R_][L_];

  // ---- one-time loads ----
  if (tid < 128) {
    biasC[tid] = lstm_bias[(tid >> 5) * H_ + s * HC_ + (tid & 31)];
    UL[tid] = score_U[tid];
    pbL[tid] = pred_b[tid];
  }
  for (int i = tid; i < R_ * T_; i += 512)
    charsL[i >> 8][i & 255] = chars[(row0 + (i >> 8)) * T_ + (i & 255)];
  for (int i = tid; i < R_ * 4 * 512; i += 512) ((float*)ringVt)[i] = 0.0f;
  __syncthreads();

  // ---- bos step (x=bos, c0=h0=0): h1/c1, pred0, zh1 ----
  float* zb = (float*)zring;   // 1024-float scratch
  for (int c2 = tid; c2 < Z4_; c2 += 512) {
    float a = lstm_bias[c2];
    #pragma unroll 8
    for (int k = 0; k < DC_; ++k) a = fmaf(bos[k], Kmat[(size_t)k * Z4_ + c2], a);
    zb[c2] = a;
  }
  __syncthreads();
  if (tid < H_) {
    float zi = zb[tid], zj = zb[H_ + tid], zo = zb[3 * H_ + tid];
    float nc = sigm(zi) * tanhf(zj);
    float nh = tanhf(nc) * sigm(zo);
    h1tmp[tid] = nh;
    int hl = tid - s * HC_;
    if (hl >= 0 && hl < HC_) {
      #pragma unroll
      for (int q = 0; q < 4; ++q)
        #pragma unroll
        for (int r = 0; r < R_; ++r) cring[q][r][hl] = nc;
    }
  }
  __syncthreads();
  { // pred0 partials (one-time full matvec)
    int kq = tid >> 7, e = tid & 127;
    float a = 0.0f;
    #pragma unroll 8
    for (int k = kq * 64; k < kq * 64 + 64; ++k)
      a = fmaf(h1tmp[k], pred_W[(size_t)k * DW_ + e], a);
    part[kq][0][e] = a;
  }
  __syncthreads();
  if (tid < 128) {
    float p = pbL[tid] + part[0][0][tid] + part[1][0][tid] + part[2][0][tid] + part[3][0][tid];
    p = tanhf(p);
    #pragma unroll
    for (int q = 0; q < 4; ++q)
      #pragma unroll
      for (int r = 0; r < R_; ++r) pring[q][r][tid] = p;
  }
  __syncthreads();
  float zh1acc;
  { // zh1 = Kh @ h1 on my 128 cols (readlane broadcast)
    int kq = tid >> 7, c = tid & 127;
    int colg = (c >> 5) * H_ + s * HC_ + (c & 31);
    const float* Kp = Kmat + (size_t)(DC_ + kq * 64) * Z4_ + colg;
    float v = h1tmp[kq * 64 + lane];
    float a = 0.0f;
    #pragma unroll 16
    for (int kk = 0; kk < 64; ++kk) a = fmaf(bcast(v, kk), Kp[(size_t)kk * Z4_], a);
    zh1acc = a;
  }
  __syncthreads();            // zb scratch + pred0 partials consumed
  { int kq = tid >> 7, c = tid & 127; part[kq][0][c] = zh1acc; }
  __syncthreads();
  if (tid < 128) {
    float z1 = part[0][0][tid] + part[1][0][tid] + part[2][0][tid] + part[3][0][tid];
    #pragma unroll
    for (int q = 0; q < 4; ++q)
      #pragma unroll
      for (int r = 0; r < R_; ++r) zring[q][r][tid] = z1;
  }
  __syncthreads();

  // ---- scan ----
  for (int t = 0; t < T_; ++t) {
    const int slot = t & 3;
    const int parR = (t - 1) & 1;
    const int parW = t & 1;

    // A: Vtab gather for char t; lanes 0..7 spin on partners' flag(t-1)
    #pragma unroll
    for (int j = 0; j < 4; ++j) {
      int i = tid + j * 512;
      int r = i >> 9, idx = i & 511;
      ringVt[r][slot][idx] = Vtab[(size_t)charsL[r][t] * 512 + idx];
    }
    if (t > 0 && tid < S_) {
      const unsigned tgt = (unsigned)t;
      const unsigned int* fp = &flags[tid * G_ + g];
      while (__hip_atomic_load(fp, __ATOMIC_ACQUIRE, __HIP_MEMORY_SCOPE_AGENT) < tgt)
        __builtin_amdgcn_s_sleep(1);
    }
    __syncthreads();                                   // B1

    // C: fused zh(t-1) + pred(t-1) partials; nh loaded straight from mailbox
    if (t > 0) {
      int kq = tid >> 7, c = tid & 127;
      const float* nb = nh_mb + ((size_t)parR * G_ + g) * (R_ * H_);
      float v0 = ld_a(&nb[0 * H_ + kq * 64 + lane]);
      float v1 = ld_a(&nb[1 * H_ + kq * 64 + lane]);
      float v2 = ld_a(&nb[2 * H_ + kq * 64 + lane]);
      float v3 = ld_a(&nb[3 * H_ + kq * 64 + lane]);
      int colg = (c >> 5) * H_ + s * HC_ + (c & 31);
      const float* Kp = Kmat + (size_t)(DC_ + kq * 64) * Z4_ + colg;
      const float* Wp = pred_W + (size_t)(kq * 64) * DW_ + c;
      float za0 = 0.f, za1 = 0.f, za2 = 0.f, za3 = 0.f;
      float pa0 = 0.f, pa1 = 0.f, pa2 = 0.f, pa3 = 0.f;
      #pragma unroll 16
      for (int kk = 0; kk < 64; ++kk) {
        float wk = Kp[(size_t)kk * Z4_];
        float wp = Wp[(size_t)kk * DW_];
        float b0 = bcast(v0, kk), b1 = bcast(v1, kk);
        float b2 = bcast(v2, kk), b3 = bcast(v3, kk);
        za0 = fmaf(b0, wk, za0); za1 = fmaf(b1, wk, za1);
        za2 = fmaf(b2, wk, za2); za3 = fmaf(b3, wk, za3);
        pa0 = fmaf(b0, wp, pa0); pa1 = fmaf(b1, wp, pa1);
        pa2 = fmaf(b2, wp, pa2); pa3 = fmaf(b3, wp, pa3);
      }
      part[kq][0][c] = za0; part[kq][1][c] = za1;
      part[kq][2][c] = za2; part[kq][3][c] = za3;
      ppart[kq][0][c] = pa0; ppart[kq][1][c] = pa1;
      ppart[kq][2][c] = pa2; ppart[kq][3][c] = pa3;
    }
    __syncthreads();                                   // B2

    // E: scores (pred(t-1) reduced inline by the w=0 wave, written to pring)
    {
      int wv = tid >> 6, r = wv >> 1;
      #pragma unroll
      for (int ww = 0; ww < 2; ++ww) {
        int w = (wv & 1) * 2 + ww;
        int ps = (t - 1 - w) & 3;
        float il = invlen(w);
        float acc = 0.0f;
        #pragma unroll
        for (int hf = 0; hf < 2; ++hf) {
          int e = lane + hf * 64;
          float pe;
          if (w == 0 && t > 0) {
            pe = tanhf(pbL[e] + ppart[0][r][e] + ppart[1][r][e]
                              + ppart[2][r][e] + ppart[3][r][e]);
            pring[(t - 1) & 3][r][e] = pe;
          } else {
            pe = pring[ps][r][e];
          }
          float sa = 0.0f;
          #pragma unroll
          for (int c2 = 0; c2 < L_; ++c2)
            if (c2 <= w) sa += ringVt[r][(t - c2) & 3][w * 128 + e];
          acc = fmaf(pe + UL[e], sa * il, acc);
        }
        #pragma unroll
        for (int off = 32; off; off >>= 1) acc += __shfl_down(acc, off);
        if (lane == 0) scL[r][w] = (w <= t) ? acc : NEGF;
      }
    }
    __syncthreads();                                   // B3

    // G: zring(t-1) reduce + inline vtsel + zx partials + outputs
    {
      int q = tid >> 7, c = tid & 127;
      if (t > 0)
        zring[(t - 1) & 3][q][c] =
            part[0][q][c] + part[1][q][c] + part[2][q][c] + part[3][q][c];
      if (s == 0 && tid < R_) {
        int bw = amax4(scL[tid]);
        out[(row0 + tid) * T_ + t] = scL[tid][bw];
        out[B_ * T_ + (row0 + tid) * T_ + t] = (float)(bw + 1);
      }
      int kl = q * 32 + (lane & 31);
      float vr[R_];
      #pragma unroll
      for (int r = 0; r < R_; ++r) {
        int bw = amax4(scL[r]);
        float v = 0.0f;
        #pragma unroll
        for (int c2 = 0; c2 < L_; ++c2)
          if (c2 <= bw) v += ringVt[r][(t - c2) & 3][bw * 128 + kl];
        vr[r] = v * invlen(bw);
      }
      int colg = (c >> 5) * H_ + s * HC_ + (c & 31);
      const float* Kp = Kmat + (size_t)(q * 32) * Z4_ + colg;
      float a0 = 0.f, a1 = 0.f, a2 = 0.f, a3 = 0.f;
      #pragma unroll 16
      for (int kk = 0; kk < 32; ++kk) {
        float wk = Kp[(size_t)kk * Z4_];
        a0 = fmaf(bcast(vr[0], kk), wk, a0);
        a1 = fmaf(bcast(vr[1], kk), wk, a1);
        a2 = fmaf(bcast(vr[2], kk), wk, a2);
        a3 = fmaf(bcast(vr[3], kk), wk, a3);
      }
      ppart[q][0][c] = a0; ppart[q][1][c] = a1;
      ppart[q][2][c] = a2; ppart[q][3][c] = a3;
    }
    __syncthreads();                                   // B4

    // H: z + gates; publish nh chunk, then flag
    if (tid < R_ * HC_) {
      int r = tid >> 5, hl = tid & 31;
      int bw = amax4(scL[r]);
      int zs = (t - 1 - bw) & 3;
      float zg[4];
      #pragma unroll
      for (int gi = 0; gi < 4; ++gi) {
        int c = gi * 32 + hl;
        zg[gi] = biasC[c] + zring[zs][r][c]
               + ppart[0][r][c] + ppart[1][r][c] + ppart[2][r][c] + ppart[3][r][c];
      }
      float cp = cring[zs][r][hl];
      float nc = cp * sigm(zg[2]) + sigm(zg[0]) * tanhf(zg[1]);
      float nh = tanhf(nc) * sigm(zg[3]);
      cring[slot][r][hl] = nc;
      st_a(&nh_mb[((size_t)parW * G_ + g) * (R_ * H_) + r * H_ + s * HC_ + hl], nh);
    }
    __syncthreads();                                   // B5 (drains nh stores)
    if (tid == 0)
      __hip_atomic_store(&flags[blk], (unsigned)(t + 1), __ATOMIC_RELEASE, __HIP_MEMORY_SCOPE_AGENT);
  }
}

extern "C" void kernel_launch(void* const* d_in, const int* in_sizes, int n_in,
                              void* d_out, int out_size, void* d_ws, size_t ws_size,
                              hipStream_t stream) {
  const int*   chars     = (const int*)d_in[0];
  const float* char_emb  = (const float*)d_in[1];
  const float* reset_W   = (const float*)d_in[2];
  const float* reset_b   = (const float*)d_in[3];
  const float* com_W     = (const float*)d_in[4];
  const float* com_b     = (const float*)d_in[5];
  const float* lstm_k    = (const float*)d_in[6];
  const float* lstm_bias = (const float*)d_in[7];
  const float* pred_W    = (const float*)d_in[8];
  const float* pred_b    = (const float*)d_in[9];
  const float* score_U   = (const float*)d_in[10];
  const float* bos       = (const float*)d_in[11];

  char* ws = (char*)d_ws;
  unsigned int* flags = (unsigned int*)(ws + WS_FLAGS);
  float* Vtab  = (float*)(ws + WS_VTAB);
  float* nh_mb = (float*)(ws + WS_NH);

  // d_ws is re-poisoned to 0xAA before every timed launch: flags MUST be zeroed.
  hipMemsetAsync(flags, 0, 256 * sizeof(unsigned int), stream);
  vtab_kernel<<<V_, 512, 0, stream>>>(char_emb, reset_W, reset_b, com_W, com_b, Vtab);
  seq_kernel<<<256, 512, 0, stream>>>(chars, Vtab, lstm_k, lstm_bias, pred_W,
                                      pred_b, score_U, bos, (float*)d_out,
                                      flags, nh_mb);
}